// Round 3
// baseline (63.465 us; speedup 1.0000x reference)
//
#include <hip/hip_runtime.h>

namespace {

constexpr int T   = 16384;
constexpr int B   = 8;
constexpr int C4  = 64;            // 256 fp32 channels as 64 float4
constexpr int SUB = 16;            // timesteps per wave
constexpr int NROWS = SUB + 10;    // 26 rows needed per chunk (halo 5 each side)
constexpr int WAVES_PER_BLOCK = 4; // block = 256 threads
constexpr int BLOCK_T = SUB * WAVES_PER_BLOCK; // 64 timesteps per block

template <bool GUARD>
__device__ __forceinline__ float4 ldx(const float4* __restrict__ xb, int tt) {
    if (GUARD) {
        if (tt < 0 || tt >= T) return float4{0.f, 0.f, 0.f, 0.f};
    }
    return xb[(size_t)tt * C4];
}

template <bool GUARD>
__device__ __forceinline__ void run_chunk(const float4* __restrict__ xb,
                                          float4* __restrict__ ob, int t0) {
    constexpr float INV = 1.0f / 11.0f;

    // Prefetch ALL rows of this chunk into registers: 26 independent
    // global_load_dwordx4 in flight -> latency hidden by ILP, not TLP.
    float4 r[NROWS];
    #pragma unroll
    for (int i = 0; i < NROWS; ++i) {
        r[i] = ldx<GUARD>(xb, t0 - 5 + i);
    }

    // Sliding sum entirely in registers.
    float4 s = {0.f, 0.f, 0.f, 0.f};
    #pragma unroll
    for (int i = 0; i < 11; ++i) {
        s.x += r[i].x; s.y += r[i].y; s.z += r[i].z; s.w += r[i].w;
    }
    float4 o;
    o.x = s.x * INV; o.y = s.y * INV; o.z = s.z * INV; o.w = s.w * INV;
    ob[(size_t)t0 * C4] = o;

    #pragma unroll
    for (int i = 1; i < SUB; ++i) {
        const float4 a = r[i + 10];
        const float4 d = r[i - 1];
        s.x += a.x - d.x; s.y += a.y - d.y; s.z += a.z - d.z; s.w += a.w - d.w;
        o.x = s.x * INV; o.y = s.y * INV; o.z = s.z * INV; o.w = s.w * INV;
        ob[(size_t)(t0 + i) * C4] = o;
    }
}

__global__ __launch_bounds__(256, 4) void runavg_kernel(const float4* __restrict__ x,
                                                        float4* __restrict__ out) {
    const int lane = threadIdx.x & 63;   // channel-group (float4) index
    const int wid  = threadIdx.x >> 6;   // wave within block -> time sub-chunk
    const int chunks_per_batch = T / BLOCK_T;       // 256
    const int b  = blockIdx.x / chunks_per_batch;
    const int t0 = (blockIdx.x % chunks_per_batch) * BLOCK_T + wid * SUB;

    const float4* __restrict__ xb = x   + (size_t)b * T * C4 + lane;
    float4* __restrict__       ob = out + (size_t)b * T * C4 + lane;

    // fast path: every load in [t0-5, t0+SUB+4] is in-range
    if (t0 >= 5 && t0 + SUB + 5 <= T) {
        run_chunk<false>(xb, ob, t0);
    } else {
        run_chunk<true>(xb, ob, t0);
    }
}

} // namespace

extern "C" void kernel_launch(void* const* d_in, const int* in_sizes, int n_in,
                              void* d_out, int out_size, void* d_ws, size_t ws_size,
                              hipStream_t stream) {
    const float4* x = (const float4*)d_in[0];
    float4* out = (float4*)d_out;
    const int grid = B * (T / BLOCK_T);  // 2048 blocks
    runavg_kernel<<<grid, 256, 0, stream>>>(x, out);
}

// Round 5
// 53.415 us; speedup vs baseline: 1.1882x; 1.1882x over previous
//
#include <hip/hip_runtime.h>

namespace {

constexpr int T   = 16384;
constexpr int B   = 8;
constexpr int C4  = 64;            // 256 fp32 channels as 64 float4
constexpr int SUB = 4;             // timesteps per wave (short chain -> real MLP)
constexpr int NROWS = SUB + 10;    // 14 rows per chunk (halo 5 each side)
constexpr int WAVES_PER_BLOCK = 4; // block = 256 threads
constexpr int BLOCK_T = SUB * WAVES_PER_BLOCK; // 16 timesteps per block

typedef float vfloat4 __attribute__((ext_vector_type(4)));  // native clang vector

template <bool GUARD>
__device__ __forceinline__ float4 ldx(const float4* __restrict__ xb, int tt) {
    if (GUARD) {
        if (tt < 0 || tt >= T) return float4{0.f, 0.f, 0.f, 0.f};
    }
    return xb[(size_t)tt * C4];
}

__device__ __forceinline__ void stnt(float4* p, float4 v) {
    vfloat4 nv = {v.x, v.y, v.z, v.w};
    __builtin_nontemporal_store(nv, (vfloat4*)p);
}

template <bool GUARD>
__device__ __forceinline__ void run_chunk(const float4* __restrict__ xb,
                                          float4* __restrict__ ob, int t0) {
    constexpr float INV = 1.0f / 11.0f;

    // All 14 rows loaded up-front: 14 independent global_load_dwordx4 in
    // flight per thread; short consumer chain afterwards.
    float4 r[NROWS];
    #pragma unroll
    for (int i = 0; i < NROWS; ++i) {
        r[i] = ldx<GUARD>(xb, t0 - 5 + i);
    }

    float4 s = {0.f, 0.f, 0.f, 0.f};
    #pragma unroll
    for (int i = 0; i < 11; ++i) {
        s.x += r[i].x; s.y += r[i].y; s.z += r[i].z; s.w += r[i].w;
    }
    float4 o;
    o.x = s.x * INV; o.y = s.y * INV; o.z = s.z * INV; o.w = s.w * INV;
    stnt(&ob[(size_t)t0 * C4], o);

    #pragma unroll
    for (int i = 1; i < SUB; ++i) {
        const float4 a = r[i + 10];
        const float4 d = r[i - 1];
        s.x += a.x - d.x; s.y += a.y - d.y; s.z += a.z - d.z; s.w += a.w - d.w;
        o.x = s.x * INV; o.y = s.y * INV; o.z = s.z * INV; o.w = s.w * INV;
        stnt(&ob[(size_t)(t0 + i) * C4], o);
    }
}

__global__ __launch_bounds__(256) void runavg_kernel(const float4* __restrict__ x,
                                                     float4* __restrict__ out) {
    const int lane = threadIdx.x & 63;   // channel-group (float4) index
    const int wid  = threadIdx.x >> 6;   // wave within block -> time sub-chunk
    const int chunks_per_batch = T / BLOCK_T;       // 1024
    const int b  = blockIdx.x / chunks_per_batch;
    const int t0 = (blockIdx.x % chunks_per_batch) * BLOCK_T + wid * SUB;

    const float4* __restrict__ xb = x   + (size_t)b * T * C4 + lane;
    float4* __restrict__       ob = out + (size_t)b * T * C4 + lane;

    // fast path: every load in [t0-5, t0+SUB+4] is in-range
    if (t0 >= 5 && t0 + SUB + 5 <= T) {
        run_chunk<false>(xb, ob, t0);
    } else {
        run_chunk<true>(xb, ob, t0);
    }
}

} // namespace

extern "C" void kernel_launch(void* const* d_in, const int* in_sizes, int n_in,
                              void* d_out, int out_size, void* d_ws, size_t ws_size,
                              hipStream_t stream) {
    const float4* x = (const float4*)d_in[0];
    float4* out = (float4*)d_out;
    const int grid = B * (T / BLOCK_T);  // 8192 blocks
    runavg_kernel<<<grid, 256, 0, stream>>>(x, out);
}

// Round 6
// 48.967 us; speedup vs baseline: 1.2961x; 1.0908x over previous
//
#include <hip/hip_runtime.h>

namespace {

constexpr int T   = 16384;
constexpr int B   = 8;
constexpr int C4  = 64;            // 256 fp32 channels as 64 float4
constexpr int SUB = 8;             // timesteps per wave
constexpr int NROWS = SUB + 10;    // 18 rows per chunk (halo 5 each side)
constexpr int WAVES_PER_BLOCK = 4; // block = 256 threads
constexpr int BLOCK_T = SUB * WAVES_PER_BLOCK; // 32 timesteps per block

typedef float vfloat4 __attribute__((ext_vector_type(4)));  // native clang vector

template <bool GUARD>
__device__ __forceinline__ float4 ldx(const float4* __restrict__ xb, int tt) {
    if (GUARD) {
        if (tt < 0 || tt >= T) return float4{0.f, 0.f, 0.f, 0.f};
    }
    return xb[(size_t)tt * C4];
}

__device__ __forceinline__ void stnt(float4* p, float4 v) {
    vfloat4 nv = {v.x, v.y, v.z, v.w};
    __builtin_nontemporal_store(nv, (vfloat4*)p);
}

template <bool GUARD>
__device__ __forceinline__ void run_chunk(const float4* __restrict__ xb,
                                          float4* __restrict__ ob, int t0) {
    constexpr float INV = 1.0f / 11.0f;

    // Prefetch all 18 rows. The sched_barrier below forbids the compiler
    // from sinking any of these loads into the consumer chain (the R2
    // failure: it clamped to 64 VGPR and re-serialized). 18 independent
    // global_load_dwordx4 in flight per thread.
    float4 r[NROWS];
    #pragma unroll
    for (int i = 0; i < NROWS; ++i) {
        r[i] = ldx<GUARD>(xb, t0 - 5 + i);
    }
    __builtin_amdgcn_sched_barrier(0);

    float4 s = {0.f, 0.f, 0.f, 0.f};
    #pragma unroll
    for (int i = 0; i < 11; ++i) {
        s.x += r[i].x; s.y += r[i].y; s.z += r[i].z; s.w += r[i].w;
    }
    float4 o;
    o.x = s.x * INV; o.y = s.y * INV; o.z = s.z * INV; o.w = s.w * INV;
    stnt(&ob[(size_t)t0 * C4], o);

    #pragma unroll
    for (int i = 1; i < SUB; ++i) {
        const float4 a = r[i + 10];
        const float4 d = r[i - 1];
        s.x += a.x - d.x; s.y += a.y - d.y; s.z += a.z - d.z; s.w += a.w - d.w;
        o.x = s.x * INV; o.y = s.y * INV; o.z = s.z * INV; o.w = s.w * INV;
        stnt(&ob[(size_t)(t0 + i) * C4], o);
    }
}

__global__ __launch_bounds__(256, 2) void runavg_kernel(const float4* __restrict__ x,
                                                        float4* __restrict__ out) {
    const int lane = threadIdx.x & 63;   // channel-group (float4) index
    const int wid  = threadIdx.x >> 6;   // wave within block -> time sub-chunk
    const int chunks_per_batch = T / BLOCK_T;       // 512
    const int b  = blockIdx.x / chunks_per_batch;
    const int t0 = (blockIdx.x % chunks_per_batch) * BLOCK_T + wid * SUB;

    const float4* __restrict__ xb = x   + (size_t)b * T * C4 + lane;
    float4* __restrict__       ob = out + (size_t)b * T * C4 + lane;

    // fast path: every load in [t0-5, t0+SUB+4] is in-range
    if (t0 >= 5 && t0 + SUB + 5 <= T) {
        run_chunk<false>(xb, ob, t0);
    } else {
        run_chunk<true>(xb, ob, t0);
    }
}

} // namespace

extern "C" void kernel_launch(void* const* d_in, const int* in_sizes, int n_in,
                              void* d_out, int out_size, void* d_ws, size_t ws_size,
                              hipStream_t stream) {
    const float4* x = (const float4*)d_in[0];
    float4* out = (float4*)d_out;
    const int grid = B * (T / BLOCK_T);  // 4096 blocks
    runavg_kernel<<<grid, 256, 0, stream>>>(x, out);
}